// Round 1
// baseline (323.195 us; speedup 1.0000x reference)
//
#include <hip/hip_runtime.h>
#include <math.h>

#define NUM_EMB 512
#define EDIM 64
#define BATCH 32
#define HW 4096
#define NROWS (BATCH * HW)        // 131072
#define NQ (NROWS * EDIM)         // 8388608

// numpy pairwise_sum for n=64 contiguous fp32: 8 stride-8 accumulators,
// tree combine ((r0+r1)+(r2+r3)) + ((r4+r5)+(r6+r7)). No FMA contraction.
__device__ __forceinline__ float pairwise8_64(const float* v) {
    float r0 = v[0], r1 = v[1], r2 = v[2], r3 = v[3];
    float r4 = v[4], r5 = v[5], r6 = v[6], r7 = v[7];
#pragma unroll
    for (int i = 8; i < 64; i += 8) {
        r0 = __fadd_rn(r0, v[i + 0]);
        r1 = __fadd_rn(r1, v[i + 1]);
        r2 = __fadd_rn(r2, v[i + 2]);
        r3 = __fadd_rn(r3, v[i + 3]);
        r4 = __fadd_rn(r4, v[i + 4]);
        r5 = __fadd_rn(r5, v[i + 5]);
        r6 = __fadd_rn(r6, v[i + 6]);
        r7 = __fadd_rn(r7, v[i + 7]);
    }
    return __fadd_rn(__fadd_rn(__fadd_rn(r0, r1), __fadd_rn(r2, r3)),
                     __fadd_rn(__fadd_rn(r4, r5), __fadd_rn(r6, r7)));
}

// ws_f layout: [0] = loss sum accumulator, [8..8+511] = t2[k] = ||emb_k||^2
__global__ void vq_prep(const float* __restrict__ emb, float* __restrict__ ws_f) {
    int k = blockIdx.x * blockDim.x + threadIdx.x;
    if (k == 0) ws_f[0] = 0.0f;
    if (k < NUM_EMB) {
        const float* e = emb + k * EDIM;
        float sq[EDIM];
#pragma unroll
        for (int c = 0; c < EDIM; ++c) sq[c] = __fmul_rn(e[c], e[c]);
        ws_f[8 + k] = pairwise8_64(sq);
    }
}

__global__ __launch_bounds__(256) void vq_main(const float* __restrict__ z,
                                               const float* __restrict__ emb,
                                               float* __restrict__ out,
                                               float* __restrict__ ws_f) {
    const int r = blockIdx.x * 256 + threadIdx.x;  // row in [0, NROWS)
    const int b = r >> 12;                         // batch
    const int hw = r & 4095;                       // h*64+w

    // x[c] = z[b, c, hw]  (coalesced across threads for each c)
    const float* zb = z + (size_t)b * (EDIM * HW) + hw;
    float x[EDIM];
#pragma unroll
    for (int c = 0; c < EDIM; ++c) x[c] = zb[(size_t)c * HW];

    // t1 = ||x||^2, numpy pairwise order
    float sq[EDIM];
#pragma unroll
    for (int c = 0; c < EDIM; ++c) sq[c] = __fmul_rn(x[c], x[c]);
    const float t1 = pairwise8_64(sq);

    const float* __restrict__ t2 = ws_f + 8;

    float best = INFINITY;
    int bestk = 0;

    for (int k = 0; k < NUM_EMB; k += 4) {
        // uniform addresses -> scalar loads, FMA operand from SGPR
        const float* e0 = emb + (size_t)(k + 0) * EDIM;
        const float* e1 = emb + (size_t)(k + 1) * EDIM;
        const float* e2 = emb + (size_t)(k + 2) * EDIM;
        const float* e3 = emb + (size_t)(k + 3) * EDIM;
        float a0 = 0.0f, a1 = 0.0f, a2 = 0.0f, a3 = 0.0f;
#pragma unroll
        for (int c = 0; c < EDIM; ++c) {
            a0 = __fmaf_rn(x[c], e0[c], a0);
            a1 = __fmaf_rn(x[c], e1[c], a1);
            a2 = __fmaf_rn(x[c], e2[c], a2);
            a3 = __fmaf_rn(x[c], e3[c], a3);
        }
        // d = fl(fl(t1 + t2) - fl(2*p)); strict < keeps lowest index on ties
        float d0 = __fsub_rn(__fadd_rn(t1, t2[k + 0]), __fmul_rn(2.0f, a0));
        float d1 = __fsub_rn(__fadd_rn(t1, t2[k + 1]), __fmul_rn(2.0f, a1));
        float d2 = __fsub_rn(__fadd_rn(t1, t2[k + 2]), __fmul_rn(2.0f, a2));
        float d3 = __fsub_rn(__fadd_rn(t1, t2[k + 3]), __fmul_rn(2.0f, a3));
        if (d0 < best) { best = d0; bestk = k + 0; }
        if (d1 < best) { best = d1; bestk = k + 1; }
        if (d2 < best) { best = d2; bestk = k + 2; }
        if (d3 < best) { best = d3; bestk = k + 3; }
    }

    // Epilogue: write qst (forward == fl(x + fl(q - x))), accumulate loss, idx.
    const float* eb = emb + (size_t)bestk * EDIM;
    float s = 0.0f;
#pragma unroll
    for (int c = 0; c < EDIM; ++c) {
        float q = eb[c];                      // divergent gather, L2-resident table
        float diff = __fsub_rn(q, x[c]);      // q - z
        out[(size_t)(b * EDIM + c) * HW + hw] = __fadd_rn(x[c], diff);
        s = __fmaf_rn(diff, diff, s);
    }

    out[(size_t)NQ + 2 + r] = (float)bestk;   // idx as fp32

    // wave-level reduction of loss partial, one atomic per wave
#pragma unroll
    for (int off = 32; off > 0; off >>= 1) s += __shfl_down(s, off);
    if ((threadIdx.x & 63) == 0) atomicAdd(ws_f, s);
}

__global__ void vq_final(const float* __restrict__ ws_f, float* __restrict__ out) {
    float m = ws_f[0] * (1.0f / (float)NQ);   // 2^-23, exact scaling
    out[NQ + 0] = m;
    out[NQ + 1] = m;
}

extern "C" void kernel_launch(void* const* d_in, const int* in_sizes, int n_in,
                              void* d_out, int out_size, void* d_ws, size_t ws_size,
                              hipStream_t stream) {
    const float* z = (const float*)d_in[0];     // [32, 64, 64, 64] fp32
    const float* emb = (const float*)d_in[1];   // [512, 64] fp32
    float* out = (float*)d_out;
    float* ws_f = (float*)d_ws;

    hipLaunchKernelGGL(vq_prep, dim3(1), dim3(512), 0, stream, emb, ws_f);
    hipLaunchKernelGGL(vq_main, dim3(NROWS / 256), dim3(256), 0, stream, z, emb, out, ws_f);
    hipLaunchKernelGGL(vq_final, dim3(1), dim3(1), 0, stream, ws_f, out);
}

// Round 2
// 322.621 us; speedup vs baseline: 1.0018x; 1.0018x over previous
//
#include <hip/hip_runtime.h>
#include <math.h>

#define NUM_EMB 512
#define EDIM 64
#define BATCH 32
#define HW 4096
#define NROWS (BATCH * HW)        // 131072
#define NQ (NROWS * EDIM)         // 8388608

// numpy pairwise_sum for n=64 contiguous fp32: 8 stride-8 accumulators,
// tree combine ((r0+r1)+(r2+r3)) + ((r4+r5)+(r6+r7)). No FMA contraction.
__device__ __forceinline__ float pairwise8_64(const float* v) {
    float r0 = v[0], r1 = v[1], r2 = v[2], r3 = v[3];
    float r4 = v[4], r5 = v[5], r6 = v[6], r7 = v[7];
#pragma unroll
    for (int i = 8; i < 64; i += 8) {
        r0 = __fadd_rn(r0, v[i + 0]);
        r1 = __fadd_rn(r1, v[i + 1]);
        r2 = __fadd_rn(r2, v[i + 2]);
        r3 = __fadd_rn(r3, v[i + 3]);
        r4 = __fadd_rn(r4, v[i + 4]);
        r5 = __fadd_rn(r5, v[i + 5]);
        r6 = __fadd_rn(r6, v[i + 6]);
        r7 = __fadd_rn(r7, v[i + 7]);
    }
    return __fadd_rn(__fadd_rn(__fadd_rn(r0, r1), __fadd_rn(r2, r3)),
                     __fadd_rn(__fadd_rn(r4, r5), __fadd_rn(r6, r7)));
}

// ws_f layout: [0] = loss sum accumulator, [8..8+511] = t2[k] = ||emb_k||^2
__global__ void vq_prep(const float* __restrict__ emb, float* __restrict__ ws_f) {
    int k = blockIdx.x * blockDim.x + threadIdx.x;
    if (k == 0) ws_f[0] = 0.0f;
    if (k < NUM_EMB) {
        const float* e = emb + k * EDIM;
        float sq[EDIM];
#pragma unroll
        for (int c = 0; c < EDIM; ++c) sq[c] = __fmul_rn(e[c], e[c]);
        ws_f[8 + k] = pairwise8_64(sq);
    }
}

__global__ __launch_bounds__(256, 2) void vq_main(const float* __restrict__ z,
                                                  const float* __restrict__ emb,
                                                  float* __restrict__ out,
                                                  float* __restrict__ ws_f) {
    const int r = blockIdx.x * 256 + threadIdx.x;  // row in [0, NROWS)
    const int b = r >> 12;                         // batch
    const int hw = r & 4095;                       // h*64+w

    // x[c] = z[b, c, hw]  (coalesced across threads for each c)
    const float* zb = z + (size_t)b * (EDIM * HW) + hw;
    float x[EDIM];
#pragma unroll
    for (int c = 0; c < EDIM; ++c) x[c] = zb[(size_t)c * HW];

    // t1 = ||x||^2, numpy pairwise order
    float sq[EDIM];
#pragma unroll
    for (int c = 0; c < EDIM; ++c) sq[c] = __fmul_rn(x[c], x[c]);
    const float t1 = pairwise8_64(sq);

    const float* __restrict__ t2 = ws_f + 8;

    float best = INFINITY;
    int bestk = 0;

    // Embedding rows as float4 (16 per row); addresses are wave-uniform.
    const float4* __restrict__ e4 = (const float4*)emb;

    for (int k = 0; k < NUM_EMB; k += 4) {
        const float4* p0 = e4 + (size_t)(k + 0) * 16;
        const float4* p1 = e4 + (size_t)(k + 1) * 16;
        const float4* p2 = e4 + (size_t)(k + 2) * 16;
        const float4* p3 = e4 + (size_t)(k + 3) * 16;
        float a0 = 0.0f, a1 = 0.0f, a2 = 0.0f, a3 = 0.0f;
        // Quarter-chunks: 4x float4 per row live (64 e-floats), bounded VGPR
        // pressure; full unroll lets the scheduler hoist next-quarter loads.
#pragma unroll
        for (int q = 0; q < 4; ++q) {
            float4 v0[4], v1[4], v2[4], v3[4];
#pragma unroll
            for (int j = 0; j < 4; ++j) {
                v0[j] = p0[q * 4 + j];
                v1[j] = p1[q * 4 + j];
                v2[j] = p2[q * 4 + j];
                v3[j] = p3[q * 4 + j];
            }
#pragma unroll
            for (int j = 0; j < 4; ++j) {
                const int c = q * 16 + j * 4;
                a0 = __fmaf_rn(x[c + 0], v0[j].x, a0);
                a0 = __fmaf_rn(x[c + 1], v0[j].y, a0);
                a0 = __fmaf_rn(x[c + 2], v0[j].z, a0);
                a0 = __fmaf_rn(x[c + 3], v0[j].w, a0);
                a1 = __fmaf_rn(x[c + 0], v1[j].x, a1);
                a1 = __fmaf_rn(x[c + 1], v1[j].y, a1);
                a1 = __fmaf_rn(x[c + 2], v1[j].z, a1);
                a1 = __fmaf_rn(x[c + 3], v1[j].w, a1);
                a2 = __fmaf_rn(x[c + 0], v2[j].x, a2);
                a2 = __fmaf_rn(x[c + 1], v2[j].y, a2);
                a2 = __fmaf_rn(x[c + 2], v2[j].z, a2);
                a2 = __fmaf_rn(x[c + 3], v2[j].w, a2);
                a3 = __fmaf_rn(x[c + 0], v3[j].x, a3);
                a3 = __fmaf_rn(x[c + 1], v3[j].y, a3);
                a3 = __fmaf_rn(x[c + 2], v3[j].z, a3);
                a3 = __fmaf_rn(x[c + 3], v3[j].w, a3);
            }
        }
        // d = fl(fl(t1 + t2) - fl(2*p)); strict < keeps lowest index on ties
        float d0 = __fsub_rn(__fadd_rn(t1, t2[k + 0]), __fmul_rn(2.0f, a0));
        float d1 = __fsub_rn(__fadd_rn(t1, t2[k + 1]), __fmul_rn(2.0f, a1));
        float d2 = __fsub_rn(__fadd_rn(t1, t2[k + 2]), __fmul_rn(2.0f, a2));
        float d3 = __fsub_rn(__fadd_rn(t1, t2[k + 3]), __fmul_rn(2.0f, a3));
        if (d0 < best) { best = d0; bestk = k + 0; }
        if (d1 < best) { best = d1; bestk = k + 1; }
        if (d2 < best) { best = d2; bestk = k + 2; }
        if (d3 < best) { best = d3; bestk = k + 3; }
    }

    // Epilogue: write qst (forward == fl(x + fl(q - x))), accumulate loss, idx.
    const float* eb = emb + (size_t)bestk * EDIM;
    float s = 0.0f;
#pragma unroll
    for (int c = 0; c < EDIM; ++c) {
        float q = eb[c];                      // divergent gather, L2-resident table
        float diff = __fsub_rn(q, x[c]);      // q - z
        out[(size_t)(b * EDIM + c) * HW + hw] = __fadd_rn(x[c], diff);
        s = __fmaf_rn(diff, diff, s);
    }

    out[(size_t)NQ + 2 + r] = (float)bestk;   // idx as fp32

    // wave-level reduction of loss partial, one atomic per wave
#pragma unroll
    for (int off = 32; off > 0; off >>= 1) s += __shfl_down(s, off);
    if ((threadIdx.x & 63) == 0) atomicAdd(ws_f, s);
}

__global__ void vq_final(const float* __restrict__ ws_f, float* __restrict__ out) {
    float m = ws_f[0] * (1.0f / (float)NQ);   // 2^-23, exact scaling
    out[NQ + 0] = m;
    out[NQ + 1] = m;
}

extern "C" void kernel_launch(void* const* d_in, const int* in_sizes, int n_in,
                              void* d_out, int out_size, void* d_ws, size_t ws_size,
                              hipStream_t stream) {
    const float* z = (const float*)d_in[0];     // [32, 64, 64, 64] fp32
    const float* emb = (const float*)d_in[1];   // [512, 64] fp32
    float* out = (float*)d_out;
    float* ws_f = (float*)d_ws;

    hipLaunchKernelGGL(vq_prep, dim3(1), dim3(512), 0, stream, emb, ws_f);
    hipLaunchKernelGGL(vq_main, dim3(NROWS / 256), dim3(256), 0, stream, z, emb, out, ws_f);
    hipLaunchKernelGGL(vq_final, dim3(1), dim3(1), 0, stream, ws_f, out);
}